// Round 6
// baseline (953.561 us; speedup 1.0000x reference)
//
#include <hip/hip_runtime.h>

// SAGPool on MI355X, round 5 (resubmit after broker timeout): single-launch
// monolith fixed per round-1 counters. 128 blocks (one graph each) x 1024
// threads (16 waves/CU). A block-diagonal 64x64; all feature math f32 VALU.
// LDS: A + one ping feature buffer (IN/OUT) + T + dbuf W chunk = 115 KB.
// H1/H2/H3 go to global ws for the tail readout (12 MB, L2-resident).

#define NGRAPH 128
#define EPG    1024     // edges per graph == blockDim.x
#define ETOT   131072
#define DIM    128
#define KSEL   32
#define SAS    66       // adjacency row stride (floats)
#define SWR    140      // swizzled feature row stride (floats)

// LDS layout (floats)
#define O_A    0                    // 64*66   = 4224
#define O_F0   4224                 // 64*140  = 8960  (IN/OUT ping)
#define O_T    13184                // 64*140  = 8960
#define O_W    22144                // 2*16*140 = 4480 (double-buffered W chunk)
#define O_PRE  26624                // 64
#define O_SC   26688                // 64
#define O_SEL  26752                // 64
#define O_RO   26816                // 768
#define O_MH   27584                // 1024
#define O_HM   28608                // 128
#define O_H2M  28736                // 64
#define LDS_FLOATS 28800
#define LDS_BYTES  (LDS_FLOATS * 4) // 115200

// Oct-skew swizzle: oct o (8 floats) of row k at k*140 + o*8 + (o>>2)*4.
// 16-colgroup b128 reads land 2-way on banks (free); row stride 140 (%32=12)
// spreads row-varying broadcasts.
__device__ __forceinline__ int swoff(int k, int o) {
  return k * SWR + o * 8 + ((o >> 2) << 2);
}

#define FMA8(A, xs, w0, w1) do { \
  A[0] += (xs)*(w0).x; A[1] += (xs)*(w0).y; A[2] += (xs)*(w0).z; A[3] += (xs)*(w0).w; \
  A[4] += (xs)*(w1).x; A[5] += (xs)*(w1).y; A[6] += (xs)*(w1).z; A[7] += (xs)*(w1).w; } while(0)

// Stage 16 rows (16x128) of W into a swizzled LDS chunk. 512 threads.
__device__ __forceinline__ void stage_w(float* dst, const float* __restrict__ Wg,
                                        int kc, int tid) {
  if (tid < 512) {
    const float4* src = (const float4*)(Wg + kc * 16 * DIM);
    int k = tid >> 5, q = tid & 31;
    *(float4*)&dst[swoff(k, q >> 1) + (q & 1) * 4] = src[tid];
  }
}

// One GCN layer: T = IN@W (IN = F0); H = relu(A@T + b) -> F0 (overwrites IN)
// and global Hg; pre[row] += H[row,:].waCol.
__device__ void gcn_layer(float* lds, const float* __restrict__ Wg,
                          const float* __restrict__ bg,
                          const float* __restrict__ waCol,
                          float* __restrict__ Hg, int tid)
{
  float* sA  = lds + O_A;
  float* F0  = lds + O_F0;
  float* sT  = lds + O_T;
  float* sW  = lds + O_W;
  float* pre = lds + O_PRE;
  const int rq = tid >> 4;        // row 0..63
  const int cb = tid & 15;        // col oct 0..15
  const int c0 = cb * 8;

  // ---- phase 1: T = IN @ W ----
  float acc[8] = {0.f,0.f,0.f,0.f,0.f,0.f,0.f,0.f};
  stage_w(sW, Wg, 0, tid);
  __syncthreads();
  for (int kc = 0; kc < 8; ++kc) {
    const float* wb = sW + (kc & 1) * 2240;
    if (kc < 7) stage_w(sW + ((kc + 1) & 1) * 2240, Wg, kc + 1, tid);
    #pragma unroll
    for (int kq = 0; kq < 4; ++kq) {
      const int kg = kc * 16 + kq * 4;
      float4 xv = *(const float4*)&F0[swoff(rq, kg >> 3) + (kg & 7)];
      float4 w0, w1;
      w0 = *(const float4*)&wb[swoff(kq * 4 + 0, cb)];
      w1 = *(const float4*)&wb[swoff(kq * 4 + 0, cb) + 4];
      FMA8(acc, xv.x, w0, w1);
      w0 = *(const float4*)&wb[swoff(kq * 4 + 1, cb)];
      w1 = *(const float4*)&wb[swoff(kq * 4 + 1, cb) + 4];
      FMA8(acc, xv.y, w0, w1);
      w0 = *(const float4*)&wb[swoff(kq * 4 + 2, cb)];
      w1 = *(const float4*)&wb[swoff(kq * 4 + 2, cb) + 4];
      FMA8(acc, xv.z, w0, w1);
      w0 = *(const float4*)&wb[swoff(kq * 4 + 3, cb)];
      w1 = *(const float4*)&wb[swoff(kq * 4 + 3, cb) + 4];
      FMA8(acc, xv.w, w0, w1);
    }
    __syncthreads();
  }
  *(float4*)&sT[swoff(rq, cb)]     = make_float4(acc[0], acc[1], acc[2], acc[3]);
  *(float4*)&sT[swoff(rq, cb) + 4] = make_float4(acc[4], acc[5], acc[6], acc[7]);
  __syncthreads();

  // ---- phase 2: H = relu(A @ T + b); pre += H . wa ----
  float4 bv0 = *(const float4*)&bg[c0];
  float4 bv1 = *(const float4*)&bg[c0 + 4];
  float a2[8];
  a2[0] = bv0.x; a2[1] = bv0.y; a2[2] = bv0.z; a2[3] = bv0.w;
  a2[4] = bv1.x; a2[5] = bv1.y; a2[6] = bv1.z; a2[7] = bv1.w;
  #pragma unroll 4
  for (int j = 0; j < 64; ++j) {
    float a = sA[rq * SAS + j];
    float4 t0 = *(const float4*)&sT[swoff(j, cb)];
    float4 t1 = *(const float4*)&sT[swoff(j, cb) + 4];
    FMA8(a2, a, t0, t1);
  }
  float4 o0, o1;
  o0.x = fmaxf(a2[0], 0.f); o0.y = fmaxf(a2[1], 0.f);
  o0.z = fmaxf(a2[2], 0.f); o0.w = fmaxf(a2[3], 0.f);
  o1.x = fmaxf(a2[4], 0.f); o1.y = fmaxf(a2[5], 0.f);
  o1.z = fmaxf(a2[6], 0.f); o1.w = fmaxf(a2[7], 0.f);
  *(float4*)&F0[swoff(rq, cb)]     = o0;   // IN is dead; reuse as OUT
  *(float4*)&F0[swoff(rq, cb) + 4] = o1;
  *(float4*)&Hg[rq * DIM + c0]     = o0;   // for tail readout
  *(float4*)&Hg[rq * DIM + c0 + 4] = o1;
  float4 wa0 = *(const float4*)&waCol[c0];
  float4 wa1 = *(const float4*)&waCol[c0 + 4];
  float pp = o0.x*wa0.x + o0.y*wa0.y + o0.z*wa0.z + o0.w*wa0.w
           + o1.x*wa1.x + o1.y*wa1.y + o1.z*wa1.z + o1.w*wa1.w;
  pp += __shfl_xor(pp, 1);
  pp += __shfl_xor(pp, 2);
  pp += __shfl_xor(pp, 4);
  pp += __shfl_xor(pp, 8);
  if (cb == 0) pre[rq] += pp;
  __syncthreads();
}

extern "C" __global__ void __launch_bounds__(1024, 4)
sagpool(const float* __restrict__ x,  const int* __restrict__ ei,
        const float* __restrict__ W1, const float* __restrict__ b1,
        const float* __restrict__ W2, const float* __restrict__ b2,
        const float* __restrict__ W3, const float* __restrict__ b3,
        const float* __restrict__ Wa, const float* __restrict__ ba,
        const float* __restrict__ M1, const float* __restrict__ c1,
        const float* __restrict__ M2, const float* __restrict__ c2,
        const float* __restrict__ M3, const float* __restrict__ c3,
        float* __restrict__ h1w, float* __restrict__ h2w,
        float* __restrict__ h3w, float* __restrict__ out)
{
  extern __shared__ float lds[];
  const int g = blockIdx.x, tid = threadIdx.x;
  float* sA  = lds + O_A;
  float* F0  = lds + O_F0;
  float* pre = lds + O_PRE;
  float* sc  = lds + O_SC;   // dinv, later score
  float* sel = lds + O_SEL;
  float* ro  = lds + O_RO;
  float* mh  = lds + O_MH;
  float* hm  = lds + O_HM;
  float* h2m = lds + O_H2M;

  // ---- adjacency: build, +I, D^-1/2 normalize ----
  for (int i = tid; i < 64 * SAS; i += 1024) sA[i] = 0.f;
  if (tid < 64) pre[tid] = 0.f;
  __syncthreads();
  {
    int s = ei[g * EPG + tid] & 63;          // EPG == blockDim.x
    int d = ei[ETOT + g * EPG + tid] & 63;
    sA[s * SAS + d] = 1.0f;
    sA[d * SAS + s] = 1.0f;
  }
  __syncthreads();
  if (tid < 64) sA[tid * SAS + tid] += 1.0f; // +I (self-edge -> 2, matches ref)
  __syncthreads();
  {
    int r = tid >> 4, q = tid & 15;
    float sum = sA[r * SAS + q * 4]     + sA[r * SAS + q * 4 + 1]
              + sA[r * SAS + q * 4 + 2] + sA[r * SAS + q * 4 + 3];
    sum += __shfl_xor(sum, 1);
    sum += __shfl_xor(sum, 2);
    sum += __shfl_xor(sum, 4);
    sum += __shfl_xor(sum, 8);
    if (q == 0) sc[r] = 1.0f / sqrtf(sum);
  }
  __syncthreads();
  for (int i = tid; i < 4096; i += 1024) {
    int r = i >> 6, c = i & 63;
    sA[r * SAS + c] *= sc[r] * sc[c];
  }
  { // stage x into F0 (swizzled)
    const float4* xg = (const float4*)(x + g * 64 * DIM);
    for (int i = tid; i < 2048; i += 1024) {
      int k = i >> 5, q = i & 31;
      *(float4*)&F0[swoff(k, q >> 1) + (q & 1) * 4] = xg[i];
    }
  }
  __syncthreads();

  // ---- 3 GCN layers ----
  gcn_layer(lds, W1, b1, Wa,           h1w + g * 8192, tid);
  gcn_layer(lds, W2, b2, Wa + DIM,     h2w + g * 8192, tid);
  gcn_layer(lds, W3, b3, Wa + 2 * DIM, h3w + g * 8192, tid);

  // ---- score = tanh(A @ pre + ba) ----
  {
    int r = tid >> 4, q = tid & 15;
    float p = sA[r * SAS + q * 4]     * pre[q * 4]
            + sA[r * SAS + q * 4 + 1] * pre[q * 4 + 1]
            + sA[r * SAS + q * 4 + 2] * pre[q * 4 + 2]
            + sA[r * SAS + q * 4 + 3] * pre[q * 4 + 3];
    p += __shfl_xor(p, 1);
    p += __shfl_xor(p, 2);
    p += __shfl_xor(p, 4);
    p += __shfl_xor(p, 8);
    if (q == 0) sc[r] = tanhf(p + ba[0]);
  }
  __syncthreads();

  // ---- top-K by rank (value desc, index asc = lax.top_k tie order) ----
  if (tid < 64) {
    float mys = sc[tid];
    int cnt = 0;
    for (int j = 0; j < 64; ++j) {
      float sj = sc[j];
      cnt += (sj > mys || (sj == mys && j < tid)) ? 1 : 0;
    }
    sel[tid] = (cnt < KSEL) ? 1.0f : 0.0f;
  }
  __syncthreads();

  // ---- readout: mean || max of score-scaled selected rows (H from global) ----
  if (tid < 768) {
    int c = tid >> 1, half = tid & 1;         // c in 0..383
    int which = c >> 7, cc = c & 127;
    const float* hb = ((which == 0) ? h1w : (which == 1) ? h2w : h3w) + g * 8192;
    float sum = 0.f, mx = -1e30f;
    for (int i = half * 32; i < half * 32 + 32; ++i) {
      if (sel[i] > 0.5f) {
        float v = sc[i] * hb[i * DIM + cc];
        sum += v;
        mx = fmaxf(mx, v);
      }
    }
    sum += __shfl_xor(sum, 1);
    mx = fmaxf(mx, __shfl_xor(mx, 1));
    if (half == 0) {
      ro[c]       = sum * (1.0f / KSEL);
      ro[384 + c] = mx;
    }
  }
  __syncthreads();

  // ---- MLP: 768 -> 128 -> 64 -> 10 ----
  {
    int j = tid & 127, oc = tid >> 7;         // 8 k-chunks of 96
    float a = 0.f;
    int k0 = oc * 96;
    for (int k = k0; k < k0 + 96; k += 4) {
      float4 r4 = *(const float4*)&ro[k];
      a += r4.x * M1[(k + 0) * DIM + j];
      a += r4.y * M1[(k + 1) * DIM + j];
      a += r4.z * M1[(k + 2) * DIM + j];
      a += r4.w * M1[(k + 3) * DIM + j];
    }
    mh[oc * 128 + j] = a;
  }
  __syncthreads();
  if (tid < 128) {
    float v = c1[tid];
    #pragma unroll
    for (int q = 0; q < 8; ++q) v += mh[q * 128 + tid];
    hm[tid] = fmaxf(v, 0.f);
  }
  __syncthreads();
  if (tid < 64) {
    float a = c2[tid];
    for (int k = 0; k < 128; ++k) a += hm[k] * M2[k * 64 + tid];
    h2m[tid] = fmaxf(a, 0.f);
  }
  __syncthreads();
  if (tid < 10) {
    float a = c3[tid];
    for (int k = 0; k < 64; ++k) a += h2m[k] * M3[k * 10 + tid];
    out[g * 10 + tid] = a;
  }
}

extern "C" void kernel_launch(void* const* d_in, const int* in_sizes, int n_in,
                              void* d_out, int out_size, void* d_ws, size_t ws_size,
                              hipStream_t stream) {
  const float* x  = (const float*)d_in[0];
  const int*   ei = (const int*)d_in[1];
  // d_in[2] (batch) unused: graphs are contiguous 64-node blocks
  const float* W1 = (const float*)d_in[3];
  const float* b1 = (const float*)d_in[4];
  const float* W2 = (const float*)d_in[5];
  const float* b2 = (const float*)d_in[6];
  const float* W3 = (const float*)d_in[7];
  const float* b3 = (const float*)d_in[8];
  const float* Wa = (const float*)d_in[9];
  const float* ba = (const float*)d_in[10];
  const float* M1 = (const float*)d_in[11];
  const float* c1 = (const float*)d_in[12];
  const float* M2 = (const float*)d_in[13];
  const float* c2 = (const float*)d_in[14];
  const float* M3 = (const float*)d_in[15];
  const float* c3 = (const float*)d_in[16];
  float* out = (float*)d_out;

  float* ws  = (float*)d_ws;
  float* h1w = ws;                    // 128*64*128 = 1M floats each
  float* h2w = ws + 1048576;
  float* h3w = ws + 2097152;

  (void)hipFuncSetAttribute(reinterpret_cast<const void*>(sagpool),
                            hipFuncAttributeMaxDynamicSharedMemorySize, LDS_BYTES);
  sagpool<<<NGRAPH, 1024, LDS_BYTES, stream>>>(x, ei, W1, b1, W2, b2, W3, b3,
                                               Wa, ba, M1, c1, M2, c2, M3, c3,
                                               h1w, h2w, h3w, out);
}

// Round 7
// 188.508 us; speedup vs baseline: 5.0585x; 5.0585x over previous
//
#include <hip/hip_runtime.h>

// SAGPool on MI355X, round 7: round-1 monolith structure (proven 80 us,
// 96 VGPR, no spill) with ONE change: 1024 threads/block (4 waves/SIMD)
// and 1 row x 8 cols per thread. __launch_bounds__(1024) with NO min-waves
// arg (round 6's (1024,4) forced a 64-VGPR budget -> scratch spill -> 1.9 GB
// of HBM traffic and 11x slowdown). Plain round-1 LDS layouts (known 3.07M
// conflict cycles); H1/H2/H3 in global ws for the tail readout.

#define NGRAPH 128
#define EPG    1024     // edges per graph == blockDim.x
#define ETOT   131072
#define DIM    128
#define KSEL   32
#define SA     68       // adjacency row stride (floats)
#define SH     132      // feature row stride (floats)

// LDS layout (floats)
#define O_A    0                    // 64*68  = 4352
#define O_W    4352                 // 16*128 = 2048
#define O_T    6400                 // 64*132 = 8448
#define O_F0   14848                // 64*132 = 8448 (IN/OUT ping)
#define O_PRE  23296                // 64
#define O_SC   23360                // 64
#define O_SEL  23424                // 64
#define O_RO   23488                // 768
#define O_MH   24256                // 1024
#define O_HM   25280                // 128
#define O_H2M  25408                // 64
#define LDS_FLOATS 25472
#define LDS_BYTES  (LDS_FLOATS * 4) // 101888

#define FMA8(A, xs, w0, w1) do { \
  A[0] += (xs)*(w0).x; A[1] += (xs)*(w0).y; A[2] += (xs)*(w0).z; A[3] += (xs)*(w0).w; \
  A[4] += (xs)*(w1).x; A[5] += (xs)*(w1).y; A[6] += (xs)*(w1).z; A[7] += (xs)*(w1).w; } while(0)

// One GCN layer: T = F0 @ W; H = relu(A@T + b) -> F0 (overwrites IN) and
// global Hg; pre[row] += H[row,:].waCol.  1024 threads: rq = row, cb = oct.
__device__ void gcn_layer(float* lds, const float* __restrict__ Wg,
                          const float* __restrict__ bg,
                          const float* __restrict__ waCol,
                          float* __restrict__ Hg, int tid)
{
  float* sA  = lds + O_A;
  float* sW  = lds + O_W;
  float* sT  = lds + O_T;
  float* F0  = lds + O_F0;
  float* pre = lds + O_PRE;
  const int rq = tid >> 4;        // row 0..63
  const int cb = tid & 15;        // col oct 0..15
  const int c0 = cb * 8;

  // ---- phase 1: T = F0 @ W (64x128 @ 128x128) ----
  float acc[8] = {0.f,0.f,0.f,0.f,0.f,0.f,0.f,0.f};
  for (int kc = 0; kc < 8; ++kc) {
    if (tid < 512) {   // stage 16 rows of W (plain [16][128])
      const float4* src = (const float4*)(Wg + kc * 16 * DIM);
      ((float4*)sW)[tid] = src[tid];
    }
    __syncthreads();
    #pragma unroll
    for (int kq = 0; kq < 4; ++kq) {
      const int kl = kq * 4;
      float4 xv = *(const float4*)&F0[rq * SH + kc * 16 + kl];
      float4 w0, w1;
      w0 = *(const float4*)&sW[(kl + 0) * DIM + c0];
      w1 = *(const float4*)&sW[(kl + 0) * DIM + c0 + 4];
      FMA8(acc, xv.x, w0, w1);
      w0 = *(const float4*)&sW[(kl + 1) * DIM + c0];
      w1 = *(const float4*)&sW[(kl + 1) * DIM + c0 + 4];
      FMA8(acc, xv.y, w0, w1);
      w0 = *(const float4*)&sW[(kl + 2) * DIM + c0];
      w1 = *(const float4*)&sW[(kl + 2) * DIM + c0 + 4];
      FMA8(acc, xv.z, w0, w1);
      w0 = *(const float4*)&sW[(kl + 3) * DIM + c0];
      w1 = *(const float4*)&sW[(kl + 3) * DIM + c0 + 4];
      FMA8(acc, xv.w, w0, w1);
    }
    __syncthreads();
  }
  *(float4*)&sT[rq * SH + c0]     = make_float4(acc[0], acc[1], acc[2], acc[3]);
  *(float4*)&sT[rq * SH + c0 + 4] = make_float4(acc[4], acc[5], acc[6], acc[7]);
  __syncthreads();

  // ---- phase 2: H = relu(A @ T + b); pre += H . wa ----
  float4 bv0 = *(const float4*)&bg[c0];
  float4 bv1 = *(const float4*)&bg[c0 + 4];
  float a2[8];
  a2[0] = bv0.x; a2[1] = bv0.y; a2[2] = bv0.z; a2[3] = bv0.w;
  a2[4] = bv1.x; a2[5] = bv1.y; a2[6] = bv1.z; a2[7] = bv1.w;
  #pragma unroll 4
  for (int j = 0; j < 64; ++j) {
    float a = sA[rq * SA + j];
    float4 t0 = *(const float4*)&sT[j * SH + c0];
    float4 t1 = *(const float4*)&sT[j * SH + c0 + 4];
    FMA8(a2, a, t0, t1);
  }
  float4 o0, o1;
  o0.x = fmaxf(a2[0], 0.f); o0.y = fmaxf(a2[1], 0.f);
  o0.z = fmaxf(a2[2], 0.f); o0.w = fmaxf(a2[3], 0.f);
  o1.x = fmaxf(a2[4], 0.f); o1.y = fmaxf(a2[5], 0.f);
  o1.z = fmaxf(a2[6], 0.f); o1.w = fmaxf(a2[7], 0.f);
  *(float4*)&F0[rq * SH + c0]     = o0;   // IN dead after phase 1; reuse as OUT
  *(float4*)&F0[rq * SH + c0 + 4] = o1;
  *(float4*)&Hg[rq * DIM + c0]     = o0;  // for tail readout
  *(float4*)&Hg[rq * DIM + c0 + 4] = o1;
  float4 wa0 = *(const float4*)&waCol[c0];
  float4 wa1 = *(const float4*)&waCol[c0 + 4];
  float pp = o0.x*wa0.x + o0.y*wa0.y + o0.z*wa0.z + o0.w*wa0.w
           + o1.x*wa1.x + o1.y*wa1.y + o1.z*wa1.z + o1.w*wa1.w;
  pp += __shfl_xor(pp, 1);
  pp += __shfl_xor(pp, 2);
  pp += __shfl_xor(pp, 4);
  pp += __shfl_xor(pp, 8);
  if (cb == 0) pre[rq] += pp;
  __syncthreads();   // F0 visible to next layer; sW safe to overwrite
}

extern "C" __global__ void __launch_bounds__(1024)
sagpool(const float* __restrict__ x,  const int* __restrict__ ei,
        const float* __restrict__ W1, const float* __restrict__ b1,
        const float* __restrict__ W2, const float* __restrict__ b2,
        const float* __restrict__ W3, const float* __restrict__ b3,
        const float* __restrict__ Wa, const float* __restrict__ ba,
        const float* __restrict__ M1, const float* __restrict__ c1,
        const float* __restrict__ M2, const float* __restrict__ c2,
        const float* __restrict__ M3, const float* __restrict__ c3,
        float* __restrict__ h1w, float* __restrict__ h2w,
        float* __restrict__ h3w, float* __restrict__ out)
{
  extern __shared__ float lds[];
  const int g = blockIdx.x, tid = threadIdx.x;
  float* sA  = lds + O_A;
  float* F0  = lds + O_F0;
  float* pre = lds + O_PRE;
  float* sc  = lds + O_SC;   // dinv, later score
  float* sel = lds + O_SEL;
  float* ro  = lds + O_RO;
  float* mh  = lds + O_MH;
  float* hm  = lds + O_HM;
  float* h2m = lds + O_H2M;

  // ---- adjacency: build, +I, D^-1/2 normalize ----
  for (int i = tid; i < 64 * SA; i += 1024) sA[i] = 0.f;
  if (tid < 64) pre[tid] = 0.f;
  __syncthreads();
  {
    int s = ei[g * EPG + tid] & 63;           // EPG == blockDim.x
    int d = ei[ETOT + g * EPG + tid] & 63;
    sA[s * SA + d] = 1.0f;
    sA[d * SA + s] = 1.0f;
  }
  __syncthreads();
  if (tid < 64) sA[tid * SA + tid] += 1.0f;   // +I (self-edge -> 2, matches ref)
  __syncthreads();
  {
    int r = tid >> 4, q = tid & 15;
    float sum = sA[r * SA + q * 4]     + sA[r * SA + q * 4 + 1]
              + sA[r * SA + q * 4 + 2] + sA[r * SA + q * 4 + 3];
    sum += __shfl_xor(sum, 1);
    sum += __shfl_xor(sum, 2);
    sum += __shfl_xor(sum, 4);
    sum += __shfl_xor(sum, 8);
    if (q == 0) sc[r] = 1.0f / sqrtf(sum);
  }
  __syncthreads();
  for (int i = tid; i < 4096; i += 1024) {
    int r = i >> 6, c = i & 63;
    sA[r * SA + c] *= sc[r] * sc[c];
  }
  { // stage x into F0 [64][132]
    const float4* xg = (const float4*)(x + g * 64 * DIM);
    for (int i = tid; i < 2048; i += 1024) {
      int r = i >> 5, q = i & 31;
      *(float4*)&F0[r * SH + q * 4] = xg[i];
    }
  }
  __syncthreads();

  // ---- 3 GCN layers ----
  gcn_layer(lds, W1, b1, Wa,           h1w + g * 8192, tid);
  gcn_layer(lds, W2, b2, Wa + DIM,     h2w + g * 8192, tid);
  gcn_layer(lds, W3, b3, Wa + 2 * DIM, h3w + g * 8192, tid);

  // ---- score = tanh(A @ pre + ba) ----
  {
    int r = tid >> 4, q = tid & 15;
    float p = sA[r * SA + q * 4]     * pre[q * 4]
            + sA[r * SA + q * 4 + 1] * pre[q * 4 + 1]
            + sA[r * SA + q * 4 + 2] * pre[q * 4 + 2]
            + sA[r * SA + q * 4 + 3] * pre[q * 4 + 3];
    p += __shfl_xor(p, 1);
    p += __shfl_xor(p, 2);
    p += __shfl_xor(p, 4);
    p += __shfl_xor(p, 8);
    if (q == 0) sc[r] = tanhf(p + ba[0]);
  }
  __syncthreads();

  // ---- top-K by rank (value desc, index asc = lax.top_k tie order) ----
  if (tid < 64) {
    float mys = sc[tid];
    int cnt = 0;
    for (int j = 0; j < 64; ++j) {
      float sj = sc[j];
      cnt += (sj > mys || (sj == mys && j < tid)) ? 1 : 0;
    }
    sel[tid] = (cnt < KSEL) ? 1.0f : 0.0f;
  }
  __syncthreads();

  // ---- readout: mean || max of score-scaled selected rows (H from global) ----
  if (tid < 768) {
    int c = tid >> 1, half = tid & 1;          // c in 0..383
    int which = c >> 7, cc = c & 127;
    const float* hb = ((which == 0) ? h1w : (which == 1) ? h2w : h3w) + g * 8192;
    float sum = 0.f, mx = -1e30f;
    for (int i = half * 32; i < half * 32 + 32; ++i) {
      if (sel[i] > 0.5f) {
        float v = sc[i] * hb[i * DIM + cc];
        sum += v;
        mx = fmaxf(mx, v);
      }
    }
    sum += __shfl_xor(sum, 1);
    mx = fmaxf(mx, __shfl_xor(mx, 1));
    if (half == 0) {
      ro[c]       = sum * (1.0f / KSEL);
      ro[384 + c] = mx;
    }
  }
  __syncthreads();

  // ---- MLP: 768 -> 128 -> 64 -> 10 ----
  {
    int j = tid & 127, oc = tid >> 7;          // 8 k-chunks of 96
    float a = 0.f;
    int k0 = oc * 96;
    for (int k = k0; k < k0 + 96; k += 4) {
      float4 r4 = *(const float4*)&ro[k];
      a += r4.x * M1[(k + 0) * DIM + j];
      a += r4.y * M1[(k + 1) * DIM + j];
      a += r4.z * M1[(k + 2) * DIM + j];
      a += r4.w * M1[(k + 3) * DIM + j];
    }
    mh[oc * 128 + j] = a;
  }
  __syncthreads();
  if (tid < 128) {
    float v = c1[tid];
    #pragma unroll
    for (int q = 0; q < 8; ++q) v += mh[q * 128 + tid];
    hm[tid] = fmaxf(v, 0.f);
  }
  __syncthreads();
  if (tid < 64) {
    float a = c2[tid];
    for (int k = 0; k < 128; ++k) a += hm[k] * M2[k * 64 + tid];
    h2m[tid] = fmaxf(a, 0.f);
  }
  __syncthreads();
  if (tid < 10) {
    float a = c3[tid];
    for (int k = 0; k < 64; ++k) a += h2m[k] * M3[k * 10 + tid];
    out[g * 10 + tid] = a;
  }
}

extern "C" void kernel_launch(void* const* d_in, const int* in_sizes, int n_in,
                              void* d_out, int out_size, void* d_ws, size_t ws_size,
                              hipStream_t stream) {
  const float* x  = (const float*)d_in[0];
  const int*   ei = (const int*)d_in[1];
  // d_in[2] (batch) unused: graphs are contiguous 64-node blocks
  const float* W1 = (const float*)d_in[3];
  const float* b1 = (const float*)d_in[4];
  const float* W2 = (const float*)d_in[5];
  const float* b2 = (const float*)d_in[6];
  const float* W3 = (const float*)d_in[7];
  const float* b3 = (const float*)d_in[8];
  const float* Wa = (const float*)d_in[9];
  const float* ba = (const float*)d_in[10];
  const float* M1 = (const float*)d_in[11];
  const float* c1 = (const float*)d_in[12];
  const float* M2 = (const float*)d_in[13];
  const float* c2 = (const float*)d_in[14];
  const float* M3 = (const float*)d_in[15];
  const float* c3 = (const float*)d_in[16];
  float* out = (float*)d_out;

  float* ws  = (float*)d_ws;
  float* h1w = ws;                    // 128*64*128 = 1M floats each
  float* h2w = ws + 1048576;
  float* h3w = ws + 2097152;

  (void)hipFuncSetAttribute(reinterpret_cast<const void*>(sagpool),
                            hipFuncAttributeMaxDynamicSharedMemorySize, LDS_BYTES);
  sagpool<<<NGRAPH, 1024, LDS_BYTES, stream>>>(x, ei, W1, b1, W2, b2, W3, b3,
                                               Wa, ba, M1, c1, M2, c2, M3, c3,
                                               h1w, h2w, h3w, out);
}

// Round 8
// 153.847 us; speedup vs baseline: 6.1981x; 1.2253x over previous
//
#include <hip/hip_runtime.h>

// SAGPool on MI355X, round 8: broadcast-oriented monolith.
// Evidence (R1 vs R7): kernel is LDS-read-bound; column-group b128 reads of
// W/T are 4-way conflicted and dominate. Fix: wave = 64 rows x 1 col-oct
// (1024 thr = 16 waves), so W (phase 1) and T (phase 2) reads are wave-uniform
// -> LDS broadcast (free). Per-row reads (F0 rows, A rows) spread banks via
// strides 132/68. W staged whole (64 KB, plain) once per layer: 3 syncs/layer.

#define NGRAPH 128
#define EPG    1024
#define ETOT   131072
#define DIM    128
#define KSEL   32
#define SA     68       // A row stride
#define SF     132      // F0/T row stride

// LDS layout (floats)
#define O_A    0                     // 64*68  = 4352
#define O_F0   4352                  // 64*132 = 8448
#define O_T    12800                 // 64*132 = 8448
#define O_W    21248                 // 128*128 = 16384 (plain; broadcast reads)
#define O_PPAR 37632                 // 16*64 = 1024 (per-wave pre partials)
#define O_PRE  38656                 // 64
#define O_SC   38720                 // 64
#define O_SEL  38784                 // 64
#define LDS_FLOATS 38848
#define LDS_BYTES  (LDS_FLOATS * 4)  // 155392 (< 163840)
// tail scratch aliases the dead W region (layers done):
#define O_RO   O_W                   // 768
#define O_MH   (O_W + 768)           // 1024
#define O_HM   (O_W + 1792)          // 128
#define O_H2M  (O_W + 1920)          // 64

#define FMA8(A, xs, w0, w1) do { \
  A[0] += (xs)*(w0).x; A[1] += (xs)*(w0).y; A[2] += (xs)*(w0).z; A[3] += (xs)*(w0).w; \
  A[4] += (xs)*(w1).x; A[5] += (xs)*(w1).y; A[6] += (xs)*(w1).z; A[7] += (xs)*(w1).w; } while(0)

// One GCN layer. lane r = tid&63 (row), wave w = tid>>6 (col-oct).
// T = F0 @ W ; H = relu(A@T + b) -> F0 (in-place) + global Hg;
// pre[r] += H[r,:].waCol (via per-wave partials).
__device__ void gcn_layer(float* lds, const float* __restrict__ Wg,
                          const float* __restrict__ bg,
                          const float* __restrict__ waCol,
                          float* __restrict__ Hg, int tid)
{
  float* sA   = lds + O_A;
  float* F0   = lds + O_F0;
  float* sT   = lds + O_T;
  float* sW   = lds + O_W;
  float* ppar = lds + O_PPAR;
  float* pre  = lds + O_PRE;
  const int r  = tid & 63;
  const int w  = tid >> 6;
  const int c0 = w * 8;

  { // stage full W (plain [128][128]); 4 float4 per thread, coalesced
    const float4* src = (const float4*)Wg;
    float4* dst = (float4*)sW;
    dst[tid]        = src[tid];
    dst[tid + 1024] = src[tid + 1024];
    dst[tid + 2048] = src[tid + 2048];
    dst[tid + 3072] = src[tid + 3072];
  }
  __syncthreads();

  // ---- phase 1: T[r][c0..c0+7] = F0[r,:] @ W[:,c0..c0+7] ----
  float acc[8] = {0.f,0.f,0.f,0.f,0.f,0.f,0.f,0.f};
  #pragma unroll 4
  for (int kq = 0; kq < 32; ++kq) {
    float4 xv = *(const float4*)&F0[r * SF + kq * 4];     // per-row, 8-quad spread
    const float* wb = sW + (kq * 4) * DIM + c0;           // wave-uniform -> broadcast
    float4 w0, w1;
    w0 = *(const float4*)&wb[0];       w1 = *(const float4*)&wb[4];
    FMA8(acc, xv.x, w0, w1);
    w0 = *(const float4*)&wb[DIM];     w1 = *(const float4*)&wb[DIM + 4];
    FMA8(acc, xv.y, w0, w1);
    w0 = *(const float4*)&wb[2 * DIM]; w1 = *(const float4*)&wb[2 * DIM + 4];
    FMA8(acc, xv.z, w0, w1);
    w0 = *(const float4*)&wb[3 * DIM]; w1 = *(const float4*)&wb[3 * DIM + 4];
    FMA8(acc, xv.w, w0, w1);
  }
  *(float4*)&sT[r * SF + c0]     = make_float4(acc[0], acc[1], acc[2], acc[3]);
  *(float4*)&sT[r * SF + c0 + 4] = make_float4(acc[4], acc[5], acc[6], acc[7]);
  __syncthreads();

  // ---- phase 2: H[r][c0..] = relu(A[r,:] @ T[:,c0..] + b) ----
  float4 bv0 = *(const float4*)&bg[c0];
  float4 bv1 = *(const float4*)&bg[c0 + 4];
  float a2[8];
  a2[0] = bv0.x; a2[1] = bv0.y; a2[2] = bv0.z; a2[3] = bv0.w;
  a2[4] = bv1.x; a2[5] = bv1.y; a2[6] = bv1.z; a2[7] = bv1.w;
  #pragma unroll 4
  for (int jq = 0; jq < 16; ++jq) {
    float4 a4 = *(const float4*)&sA[r * SA + jq * 4];     // per-row, 8-quad spread
    const float* tb = sT + (jq * 4) * SF + c0;            // wave-uniform -> broadcast
    float4 t0, t1;
    t0 = *(const float4*)&tb[0];      t1 = *(const float4*)&tb[4];
    FMA8(a2, a4.x, t0, t1);
    t0 = *(const float4*)&tb[SF];     t1 = *(const float4*)&tb[SF + 4];
    FMA8(a2, a4.y, t0, t1);
    t0 = *(const float4*)&tb[2 * SF]; t1 = *(const float4*)&tb[2 * SF + 4];
    FMA8(a2, a4.z, t0, t1);
    t0 = *(const float4*)&tb[3 * SF]; t1 = *(const float4*)&tb[3 * SF + 4];
    FMA8(a2, a4.w, t0, t1);
  }
  float4 o0, o1;
  o0.x = fmaxf(a2[0], 0.f); o0.y = fmaxf(a2[1], 0.f);
  o0.z = fmaxf(a2[2], 0.f); o0.w = fmaxf(a2[3], 0.f);
  o1.x = fmaxf(a2[4], 0.f); o1.y = fmaxf(a2[5], 0.f);
  o1.z = fmaxf(a2[6], 0.f); o1.w = fmaxf(a2[7], 0.f);
  __syncthreads();                       // all T reads done before F0 overwrite
  *(float4*)&F0[r * SF + c0]      = o0;  // F0 becomes this layer's H
  *(float4*)&F0[r * SF + c0 + 4]  = o1;
  *(float4*)&Hg[r * DIM + c0]     = o0;  // tail readout copy
  *(float4*)&Hg[r * DIM + c0 + 4] = o1;
  float4 wa0 = *(const float4*)&waCol[c0];
  float4 wa1 = *(const float4*)&waCol[c0 + 4];
  ppar[w * 64 + r] = o0.x*wa0.x + o0.y*wa0.y + o0.z*wa0.z + o0.w*wa0.w
                   + o1.x*wa1.x + o1.y*wa1.y + o1.z*wa1.z + o1.w*wa1.w;
  __syncthreads();
  if (tid < 64) {                        // reduce 16 wave-partials -> pre
    float s = 0.f;
    #pragma unroll
    for (int q = 0; q < 16; ++q) s += ppar[q * 64 + tid];
    pre[tid] += s;
  }
  // no sync needed: next write of ppar is 2 syncs away; pre[r] is same-thread.
}

extern "C" __global__ void __launch_bounds__(1024)
sagpool(const float* __restrict__ x,  const int* __restrict__ ei,
        const float* __restrict__ W1, const float* __restrict__ b1,
        const float* __restrict__ W2, const float* __restrict__ b2,
        const float* __restrict__ W3, const float* __restrict__ b3,
        const float* __restrict__ Wa, const float* __restrict__ ba,
        const float* __restrict__ M1, const float* __restrict__ c1,
        const float* __restrict__ M2, const float* __restrict__ c2,
        const float* __restrict__ M3, const float* __restrict__ c3,
        float* __restrict__ h1w, float* __restrict__ h2w,
        float* __restrict__ h3w, float* __restrict__ out)
{
  extern __shared__ float lds[];
  const int g = blockIdx.x, tid = threadIdx.x;
  float* sA  = lds + O_A;
  float* F0  = lds + O_F0;
  float* pre = lds + O_PRE;
  float* sc  = lds + O_SC;   // dinv, later score
  float* sel = lds + O_SEL;
  float* ro  = lds + O_RO;
  float* mh  = lds + O_MH;
  float* hm  = lds + O_HM;
  float* h2m = lds + O_H2M;

  // ---- adjacency: build, +I, D^-1/2 normalize ----
  for (int i = tid; i < 64 * SA; i += 1024) sA[i] = 0.f;
  if (tid < 64) pre[tid] = 0.f;
  __syncthreads();
  {
    int s = ei[g * EPG + tid] & 63;
    int d = ei[ETOT + g * EPG + tid] & 63;
    sA[s * SA + d] = 1.0f;
    sA[d * SA + s] = 1.0f;
  }
  __syncthreads();
  if (tid < 64) sA[tid * SA + tid] += 1.0f;   // +I (self-edge -> 2, matches ref)
  __syncthreads();
  {
    int r = tid >> 4, q = tid & 15;
    float sum = sA[r * SA + q * 4]     + sA[r * SA + q * 4 + 1]
              + sA[r * SA + q * 4 + 2] + sA[r * SA + q * 4 + 3];
    sum += __shfl_xor(sum, 1);
    sum += __shfl_xor(sum, 2);
    sum += __shfl_xor(sum, 4);
    sum += __shfl_xor(sum, 8);
    if (q == 0) sc[r] = 1.0f / sqrtf(sum);
  }
  __syncthreads();
  for (int i = tid; i < 4096; i += 1024) {
    int r = i >> 6, c = i & 63;
    sA[r * SA + c] *= sc[r] * sc[c];
  }
  { // stage x into F0 [64][132]
    const float4* xg = (const float4*)(x + g * 64 * DIM);
    for (int i = tid; i < 2048; i += 1024) {
      int r = i >> 5, q = i & 31;
      *(float4*)&F0[r * SF + q * 4] = xg[i];
    }
  }
  __syncthreads();

  // ---- 3 GCN layers ----
  gcn_layer(lds, W1, b1, Wa,           h1w + g * 8192, tid);
  gcn_layer(lds, W2, b2, Wa + DIM,     h2w + g * 8192, tid);
  gcn_layer(lds, W3, b3, Wa + 2 * DIM, h3w + g * 8192, tid);
  __syncthreads();                     // pre complete before score

  // ---- score = tanh(A @ pre + ba) ----
  {
    int r = tid >> 4, q = tid & 15;
    float p = sA[r * SA + q * 4]     * pre[q * 4]
            + sA[r * SA + q * 4 + 1] * pre[q * 4 + 1]
            + sA[r * SA + q * 4 + 2] * pre[q * 4 + 2]
            + sA[r * SA + q * 4 + 3] * pre[q * 4 + 3];
    p += __shfl_xor(p, 1);
    p += __shfl_xor(p, 2);
    p += __shfl_xor(p, 4);
    p += __shfl_xor(p, 8);
    if (q == 0) sc[r] = tanhf(p + ba[0]);
  }
  __syncthreads();

  // ---- top-K by rank (value desc, index asc = lax.top_k tie order) ----
  if (tid < 64) {
    float mys = sc[tid];
    int cnt = 0;
    for (int j = 0; j < 64; ++j) {
      float sj = sc[j];
      cnt += (sj > mys || (sj == mys && j < tid)) ? 1 : 0;
    }
    sel[tid] = (cnt < KSEL) ? 1.0f : 0.0f;
  }
  __syncthreads();

  // ---- readout: mean || max of score-scaled selected rows ----
  if (tid < 768) {
    int c = tid >> 1, half = tid & 1;          // c in 0..383
    int which = c >> 7, cc = c & 127;
    const float* hb = ((which == 0) ? h1w : (which == 1) ? h2w : h3w) + g * 8192;
    float sum = 0.f, mx = -1e30f;
    for (int i = half * 32; i < half * 32 + 32; ++i) {
      if (sel[i] > 0.5f) {
        float v = sc[i] * hb[i * DIM + cc];
        sum += v;
        mx = fmaxf(mx, v);
      }
    }
    sum += __shfl_xor(sum, 1);
    mx = fmaxf(mx, __shfl_xor(mx, 1));
    if (half == 0) {
      ro[c]       = sum * (1.0f / KSEL);
      ro[384 + c] = mx;
    }
  }
  __syncthreads();

  // ---- MLP: 768 -> 128 -> 64 -> 10 ----
  {
    int j = tid & 127, oc = tid >> 7;          // 8 k-chunks of 96
    float a = 0.f;
    int k0 = oc * 96;
    for (int k = k0; k < k0 + 96; k += 4) {
      float4 r4 = *(const float4*)&ro[k];
      a += r4.x * M1[(k + 0) * DIM + j];
      a += r4.y * M1[(k + 1) * DIM + j];
      a += r4.z * M1[(k + 2) * DIM + j];
      a += r4.w * M1[(k + 3) * DIM + j];
    }
    mh[oc * 128 + j] = a;
  }
  __syncthreads();
  if (tid < 128) {
    float v = c1[tid];
    #pragma unroll
    for (int q = 0; q < 8; ++q) v += mh[q * 128 + tid];
    hm[tid] = fmaxf(v, 0.f);
  }
  __syncthreads();
  if (tid < 64) {
    float a = c2[tid];
    for (int k = 0; k < 128; ++k) a += hm[k] * M2[k * 64 + tid];
    h2m[tid] = fmaxf(a, 0.f);
  }
  __syncthreads();
  if (tid < 10) {
    float a = c3[tid];
    for (int k = 0; k < 64; ++k) a += h2m[k] * M3[k * 10 + tid];
    out[g * 10 + tid] = a;
  }
}

extern "C" void kernel_launch(void* const* d_in, const int* in_sizes, int n_in,
                              void* d_out, int out_size, void* d_ws, size_t ws_size,
                              hipStream_t stream) {
  const float* x  = (const float*)d_in[0];
  const int*   ei = (const int*)d_in[1];
  // d_in[2] (batch) unused: graphs are contiguous 64-node blocks
  const float* W1 = (const float*)d_in[3];
  const float* b1 = (const float*)d_in[4];
  const float* W2 = (const float*)d_in[5];
  const float* b2 = (const float*)d_in[6];
  const float* W3 = (const float*)d_in[7];
  const float* b3 = (const float*)d_in[8];
  const float* Wa = (const float*)d_in[9];
  const float* ba = (const float*)d_in[10];
  const float* M1 = (const float*)d_in[11];
  const float* c1 = (const float*)d_in[12];
  const float* M2 = (const float*)d_in[13];
  const float* c2 = (const float*)d_in[14];
  const float* M3 = (const float*)d_in[15];
  const float* c3 = (const float*)d_in[16];
  float* out = (float*)d_out;

  float* ws  = (float*)d_ws;
  float* h1w = ws;                    // 128*64*128 = 1M floats each
  float* h2w = ws + 1048576;
  float* h3w = ws + 2097152;

  (void)hipFuncSetAttribute(reinterpret_cast<const void*>(sagpool),
                            hipFuncAttributeMaxDynamicSharedMemorySize, LDS_BYTES);
  sagpool<<<NGRAPH, 1024, LDS_BYTES, stream>>>(x, ei, W1, b1, W2, b2, W3, b3,
                                               Wa, ba, M1, c1, M2, c2, M3, c3,
                                               h1w, h2w, h3w, out);
}